// Round 22
// baseline (49.610 us; speedup 1.0000x reference)
//
#include <hip/hip_runtime.h>

#define L 512
#define D 768
#define LL (L * L)
#define LOG2E  1.44269504088896341f
#define LOG2E2 2.88539008177792681f   // 2*log2(e)
#define DH 8                           // d-split factor
#define DSEG (D / DH)                  // 96
#define QB 8                           // q-rows per block in score_k

typedef __attribute__((ext_vector_type(8))) short bf16x8;
typedef __attribute__((ext_vector_type(4))) short bf16x4;
typedef __attribute__((ext_vector_type(4))) float f32x4;
typedef __attribute__((ext_vector_type(2))) float f32x2;

__device__ __forceinline__ ushort f2bf(float f) {
    unsigned u = __builtin_bit_cast(unsigned, f);
    u += 0x7FFFu + ((u >> 16) & 1u);          // RNE
    return (ushort)(u >> 16);
}

// packed bf16 convert (RNE, same rounding as f2bf) — no builtin on gfx950
__device__ __forceinline__ unsigned cvt_pk(float lo, float hi) {
    unsigned r;
    asm("v_cvt_pk_bf16_f32 %0, %1, %2" : "=v"(r) : "v"(lo), "v"(hi));
    return r;
}

__device__ __forceinline__ f32x2 dup2(float x) { return (f32x2){x, x}; }

// ---------------- fused projection GEMM: Q, K, XWt in ONE block ---------------
// 32x64 tile, BK=64, 4 waves, grid (12,16). A = X staged ONCE per K-step
// (shared by all three products); three B tiles (Wq/Wk/Wt) staged transposed
// via register 4x4 transpose + cvt_pk; 12 MFMA per barrier pair.
// Epilogue: Qb+Eq (m=0), EkT transposed-exp2 (m=1), XWtT transposed bf16 (m=2).
__global__ __launch_bounds__(256) void gemm_fused0(
    const float* __restrict__ Xf,
    const float* __restrict__ W0, const float* __restrict__ W1,
    const float* __restrict__ W2,
    const float* __restrict__ bq, const float* __restrict__ bk,
    float* __restrict__ Qb, float* __restrict__ Eq,
    float* __restrict__ EkT, ushort* __restrict__ XWtT)
{
    const int N = D, K = D;
    __shared__ __align__(16) ushort As[32][72];
    __shared__ __align__(16) ushort Bs[3][64][76];

    const int m0 = blockIdx.y * 32;
    const int n0 = blockIdx.x * 64;
    const int t = threadIdx.x;
    const int l = t & 63, w = t >> 6;
    const int wr = w >> 1, wc = w & 1;
    const int frow = l & 15;
    const int kg = (l >> 4) * 8;

    const int srow = t >> 3, sk = (t & 7) * 8;      // A staging
    const int kq = (t >> 4) * 4, nc = (t & 15) * 4; // B staging (4k x 4n block)
    const float* ApF = Xf + (m0 + srow) * D + sk;
    const float* Wp0 = W0 + kq * D + n0 + nc;
    const float* Wp1 = W1 + kq * D + n0 + nc;
    const float* Wp2 = W2 + kq * D + n0 + nc;

    float4 pa0 = *(const float4*)(ApF + 0);
    float4 pa1 = *(const float4*)(ApF + 4);
    float4 pw[3][4];
    #pragma unroll
    for (int r = 0; r < 4; ++r) {
        pw[0][r] = *(const float4*)(Wp0 + r * D);
        pw[1][r] = *(const float4*)(Wp1 + r * D);
        pw[2][r] = *(const float4*)(Wp2 + r * D);
    }

    f32x4 acc[3][2] = {};

    for (int k0 = 0; k0 < K; k0 += 64) {
        if (k0) __syncthreads();
        {   // A: 8 fp32 -> 4 cvt_pk -> one b128 store
            uint4 av;
            av.x = cvt_pk(pa0.x, pa0.y);
            av.y = cvt_pk(pa0.z, pa0.w);
            av.z = cvt_pk(pa1.x, pa1.y);
            av.w = cvt_pk(pa1.z, pa1.w);
            *(uint4*)&As[srow][sk] = av;
        }
        #pragma unroll
        for (int m = 0; m < 3; ++m) {   // B: register 4x4 transpose per matrix
            uint2 b;
            b.x = cvt_pk(pw[m][0].x, pw[m][1].x); b.y = cvt_pk(pw[m][2].x, pw[m][3].x);
            *(uint2*)&Bs[m][nc + 0][kq] = b;
            b.x = cvt_pk(pw[m][0].y, pw[m][1].y); b.y = cvt_pk(pw[m][2].y, pw[m][3].y);
            *(uint2*)&Bs[m][nc + 1][kq] = b;
            b.x = cvt_pk(pw[m][0].z, pw[m][1].z); b.y = cvt_pk(pw[m][2].z, pw[m][3].z);
            *(uint2*)&Bs[m][nc + 2][kq] = b;
            b.x = cvt_pk(pw[m][0].w, pw[m][1].w); b.y = cvt_pk(pw[m][2].w, pw[m][3].w);
            *(uint2*)&Bs[m][nc + 3][kq] = b;
        }
        __syncthreads();
        if (k0 + 64 < K) {                  // prefetch next tile under MFMA
            pa0 = *(const float4*)(ApF + k0 + 64);
            pa1 = *(const float4*)(ApF + k0 + 68);
            #pragma unroll
            for (int r = 0; r < 4; ++r) {
                pw[0][r] = *(const float4*)(Wp0 + (k0 + 64 + r) * D);
                pw[1][r] = *(const float4*)(Wp1 + (k0 + 64 + r) * D);
                pw[2][r] = *(const float4*)(Wp2 + (k0 + 64 + r) * D);
            }
        }

        bf16x8 af[2];
        #pragma unroll
        for (int kk = 0; kk < 2; ++kk)
            af[kk] = *(const bf16x8*)&As[16 * wr + frow][32 * kk + kg];
        #pragma unroll
        for (int m = 0; m < 3; ++m)
            #pragma unroll
            for (int fc = 0; fc < 2; ++fc)
                #pragma unroll
                for (int kk = 0; kk < 2; ++kk) {
                    bf16x4 lo = *(const bf16x4*)&Bs[m][32 * wc + 16 * fc + frow][32 * kk + kg];
                    bf16x4 hi = *(const bf16x4*)&Bs[m][32 * wc + 16 * fc + frow][32 * kk + kg + 4];
                    bf16x8 bv = __builtin_shufflevector(lo, hi, 0, 1, 2, 3, 4, 5, 6, 7);
                    acc[m][fc] = __builtin_amdgcn_mfma_f32_16x16x32_bf16(af[kk], bv, acc[m][fc], 0, 0, 0);
                }
    }

    const int rg = (l >> 4) * 4;
    #pragma unroll
    for (int fc = 0; fc < 2; ++fc) {
        const int col = n0 + 32 * wc + 16 * fc + frow;
        const int row0 = m0 + 16 * wr + rg;       // multiple of 4
        // m=0: Q path
        {
            const float bv = bq[col];
            #pragma unroll
            for (int i = 0; i < 4; ++i) {
                float v = acc[0][fc][i] + bv;
                Qb[(row0 + i) * N + col] = v;
                Eq[(row0 + i) * N + col] = __builtin_amdgcn_exp2f(LOG2E2 * v);
            }
        }
        // m=1: EkT transposed exp2
        {
            const float bv = bk[col];
            float4 e;
            e.x = __builtin_amdgcn_exp2f(LOG2E2 * (acc[1][fc][0] + bv));
            e.y = __builtin_amdgcn_exp2f(LOG2E2 * (acc[1][fc][1] + bv));
            e.z = __builtin_amdgcn_exp2f(LOG2E2 * (acc[1][fc][2] + bv));
            e.w = __builtin_amdgcn_exp2f(LOG2E2 * (acc[1][fc][3] + bv));
            *(float4*)&EkT[col * L + row0] = e;
        }
        // m=2: XWtT transposed bf16
        {
            uint2 e;
            e.x = cvt_pk(acc[2][fc][0], acc[2][fc][1]);
            e.y = cvt_pk(acc[2][fc][2], acc[2][fc][3]);
            *(uint2*)&XWtT[col * L + row0] = e;
        }
    }
}

// ---------------- output GEMM: out = P @ XWt + bt + Qb, 8 waves ---------------
// 32x64 tile, BK=64, 512 threads (8 waves, each one 16x16 frag), grid (12,16).
__global__ __launch_bounds__(512) void gemm_pv(
    const ushort* __restrict__ Pbf, const ushort* __restrict__ XWtT,
    const float* __restrict__ bt, const float* __restrict__ Qb,
    float* __restrict__ out)
{
    const int N = D, K = L;
    __shared__ __align__(16) ushort As[32][72];
    __shared__ __align__(16) ushort Bs[64][72];

    const int m0 = blockIdx.y * 32;
    const int n0 = blockIdx.x * 64;
    const int t = threadIdx.x;
    const int l = t & 63, w = t >> 6;
    const int wr = w >> 2, wc = w & 3;        // 2 x 4 waves
    const int frow = l & 15;
    const int kg = (l >> 4) * 8;

    const int srA = t >> 4, skA = (t & 15) * 4;   // A: 512 x b64
    const int srB = t >> 3, skB = (t & 7) * 8;    // B: 512 x b128
    const ushort* Ap = Pbf  + (m0 + srA) * K + skA;
    const ushort* Bp = XWtT + (n0 + srB) * K + skB;

    uint2 a0 = *(const uint2*)Ap;
    uint4 b0 = *(const uint4*)Bp;

    f32x4 acc = {};

    for (int k0 = 0; k0 < K; k0 += 64) {
        if (k0) __syncthreads();
        *(uint2*)&As[srA][skA] = a0;
        *(uint4*)&Bs[srB][skB] = b0;
        __syncthreads();
        if (k0 + 64 < K) {
            a0 = *(const uint2*)(Ap + k0 + 64);
            b0 = *(const uint4*)(Bp + k0 + 64);
        }
        #pragma unroll
        for (int kk = 0; kk < 2; ++kk) {
            bf16x8 af = *(const bf16x8*)&As[16 * wr + frow][32 * kk + kg];
            bf16x8 bv = *(const bf16x8*)&Bs[16 * wc + frow][32 * kk + kg];
            acc = __builtin_amdgcn_mfma_f32_16x16x32_bf16(af, bv, acc, 0, 0, 0);
        }
    }

    const int rg = (l >> 4) * 4;
    const int col = n0 + 16 * wc + frow;
    const int row0 = m0 + 16 * wr + rg;
    const float bv = bt[col];
    #pragma unroll
    for (int i = 0; i < 4; ++i)
        out[(row0 + i) * N + col] = acc[i] + bv + Qb[(row0 + i) * N + col];
}

// ---------------- partial scores: lane = k, LDS-broadcast Eq ------------------
// PACKED-FP32 q-pairs + 4-WAY RECIPROCAL (sum w_i/A_i = (N1*CD+N2*AB)*rcp(ABCD)).
// w' = -2*LOG2E*w staged in a contiguous quad array (one b128 per d-quad).
// Partials are in log2 units -> softmax is a bare exp2.
__global__ __launch_bounds__(256) void score_k(
    const float* __restrict__ Eq, const float* __restrict__ EkT,
    const float* __restrict__ w_att, float* __restrict__ sP)
{
    __shared__ __align__(16) float eqlds[DSEG][8];   // eq q0..q7 per d
    __shared__ __align__(16) float wlds[DSEG];       // w' per d (quad-readable)
    const int kt = blockIdx.x;          // 0..1
    const int dh = blockIdx.y;          // 0..7
    const int qg = blockIdx.z;          // 0..63
    const int q0 = qg * QB;
    const int dbase = dh * DSEG;
    const int tid = threadIdx.x;
    const int lane = tid & 63, wv = tid >> 6;
    const int k = kt * 256 + wv * 64 + lane;

    {   // stage: 8 rows x 96 cols, 32 threads per row, 3 cols each
        const int row = tid >> 5;       // 0..7
        const int j   = tid & 31;
        #pragma unroll
        for (int c = 0; c < 3; ++c) {
            int d = j + 32 * c;
            eqlds[d][row] = Eq[(q0 + row) * D + dbase + d];
        }
        if (tid < 32) {
            #pragma unroll
            for (int c = 0; c < 3; ++c) {
                int d = tid + 32 * c;
                wlds[d] = (-2.f * LOG2E) * w_att[dbase + d];
            }
        }
    }
    __syncthreads();

    const float* __restrict__ ekp = EkT + dbase * L + k;
    const f32x2 one = dup2(1.f);
    f32x2 acc2[4] = {};

    #pragma unroll 2
    for (int d0 = 0; d0 < DSEG; d0 += 4) {
        f32x2 ek0 = dup2(ekp[(d0 + 0) * L]);
        f32x2 ek1 = dup2(ekp[(d0 + 1) * L]);
        f32x2 ek2 = dup2(ekp[(d0 + 2) * L]);
        f32x2 ek3 = dup2(ekp[(d0 + 3) * L]);
        f32x4 wq4 = *(const f32x4*)&wlds[d0];
        f32x2 w0 = dup2(wq4[0]), w1 = dup2(wq4[1]);
        f32x2 w2 = dup2(wq4[2]), w3 = dup2(wq4[3]);
        f32x4 Elo[4], Ehi[4];
        #pragma unroll
        for (int dd = 0; dd < 4; ++dd) {
            Elo[dd] = *(const f32x4*)&eqlds[d0 + dd][0];   // q0..q3
            Ehi[dd] = *(const f32x4*)&eqlds[d0 + dd][4];   // q4..q7
        }
        #pragma unroll
        for (int j = 0; j < 4; ++j) {
            #define GET2(dd) ((j < 2) ? (f32x2){Elo[dd][2 * j], Elo[dd][2 * j + 1]} \
                                      : (f32x2){Ehi[dd][2 * j - 4], Ehi[dd][2 * j - 3]})
            f32x2 e0 = GET2(0);
            f32x2 e1 = GET2(1);
            f32x2 e2 = GET2(2);
            f32x2 e3 = GET2(3);
            #undef GET2
            f32x2 Aa = __builtin_elementwise_fma(e0, ek0, one);
            f32x2 Bb = __builtin_elementwise_fma(e1, ek1, one);
            f32x2 Cc = __builtin_elementwise_fma(e2, ek2, one);
            f32x2 Dd = __builtin_elementwise_fma(e3, ek3, one);
            f32x2 AB = Aa * Bb, CD = Cc * Dd;
            f32x2 N1 = __builtin_elementwise_fma(w0, Bb, w1 * Aa);
            f32x2 N2 = __builtin_elementwise_fma(w2, Dd, w3 * Cc);
            f32x2 Nm = __builtin_elementwise_fma(N1, CD, N2 * AB);
            f32x2 P = AB * CD;
            f32x2 R;
            R.x = __builtin_amdgcn_rcpf(P.x);
            R.y = __builtin_amdgcn_rcpf(P.y);
            acc2[j] = __builtin_elementwise_fma(Nm, R, acc2[j]);
        }
    }

    float* __restrict__ dst = sP + dh * LL + q0 * L + k;
    #pragma unroll
    for (int j = 0; j < 4; ++j) {
        dst[(2 * j + 0) * L] = acc2[j].x;
        dst[(2 * j + 1) * L] = acc2[j].y;
    }
}

// ---------------- softmax (sum of 8 d-partials + mask) -> bf16 probs ----------
// 512 blocks (one q-row each) x 512 threads. NO max pass (bounded log2 scores).
__global__ __launch_bounds__(512) void softmax_probs(
    const float* __restrict__ sP, const float* __restrict__ mask,
    ushort* __restrict__ Pbf)
{
    __shared__ float redB[8];
    const int q = blockIdx.x;
    const int tid = threadIdx.x;
    const int lane = tid & 63, wave = tid >> 6;

    float v = LOG2E * mask[tid];
    #pragma unroll
    for (int h = 0; h < DH; ++h)
        v += sP[h * LL + q * L + tid];

    float e = __builtin_amdgcn_exp2f(v);
    float s = e;
    #pragma unroll
    for (int off = 32; off; off >>= 1)
        s += __shfl_xor(s, off);
    if (lane == 0) redB[wave] = s;
    __syncthreads();
    float t0 = redB[0];
    #pragma unroll
    for (int i = 1; i < 8; ++i) t0 += redB[i];
    Pbf[q * L + tid] = f2bf(e * __builtin_amdgcn_rcpf(t0));
}

extern "C" void kernel_launch(void* const* d_in, const int* in_sizes, int n_in,
                              void* d_out, int out_size, void* d_ws, size_t ws_size,
                              hipStream_t stream) {
    const float* X     = (const float*)d_in[0];
    const float* mask  = (const float*)d_in[1];
    const float* Wq    = (const float*)d_in[2];
    const float* bq    = (const float*)d_in[3];
    const float* Wk    = (const float*)d_in[4];
    const float* bk    = (const float*)d_in[5];
    const float* w_att = (const float*)d_in[6];
    // d_in[7] = b_att: row-constant -> softmax-invariant; dropped.
    const float* Wt    = (const float*)d_in[8];
    const float* bt    = (const float*)d_in[9];
    float* out = (float*)d_out;

    const int LD = L * D;
    float*  Qb   = (float*)d_ws;          // [L*D] fp32 Q (final addend)
    float*  Eq   = Qb + LD;               // [L*D] exp2(c*Q) row-major
    float*  EkT  = Eq + LD;               // [D][L] exp2(c*K) transposed
    float*  sP   = EkT + LD;              // [DH][L][L] partial scores (log2 units)
    ushort* XWtT = (ushort*)(sP + DH * LL); // [D][L] bf16 (X@Wt)^T
    ushort* Pbf  = XWtT + LD;             // [L][L] bf16 probs

    // Q/Eq, EkT, XWtT in ONE fused launch (A staged once, 12 MFMA per barrier)
    gemm_fused0<<<dim3(D / 64, L / 32), 256, 0, stream>>>(
        X, Wq, Wk, Wt, bq, bk, Qb, Eq, EkT, XWtT);

    // partial scores: lane = k, LDS-broadcast Eq, packed-fp32 4-way rcp
    score_k<<<dim3(2, DH, L / QB), 256, 0, stream>>>(Eq, EkT, w_att, sP);

    // softmax over the 8 partials (+mask) -> bf16 probs, 1 q-row per block
    softmax_probs<<<dim3(L), 512, 0, stream>>>(sP, mask, Pbf);

    // out = P @ XWt + bt + Q   (K=512, 8 waves)
    gemm_pv<<<dim3(D / 64, L / 32), 512, 0, stream>>>(Pbf, XWtT, bt, Qb, out);
}

// Round 23
// 45.787 us; speedup vs baseline: 1.0835x; 1.0835x over previous
//
#include <hip/hip_runtime.h>

#define L 512
#define D 768
#define LL (L * L)
#define LOG2E  1.44269504088896341f
#define LOG2E2 2.88539008177792681f   // 2*log2(e)
#define DH 8                           // d-split factor
#define DSEG (D / DH)                  // 96
#define QB 8                           // q-rows per block in score_k

typedef __attribute__((ext_vector_type(8))) short bf16x8;
typedef __attribute__((ext_vector_type(4))) short bf16x4;
typedef __attribute__((ext_vector_type(4))) float f32x4;
typedef __attribute__((ext_vector_type(2))) float f32x2;

__device__ __forceinline__ ushort f2bf(float f) {
    unsigned u = __builtin_bit_cast(unsigned, f);
    u += 0x7FFFu + ((u >> 16) & 1u);          // RNE
    return (ushort)(u >> 16);
}

// packed bf16 convert (RNE, same rounding as f2bf) — no builtin on gfx950
__device__ __forceinline__ unsigned cvt_pk(float lo, float hi) {
    unsigned r;
    asm("v_cvt_pk_bf16_f32 %0, %1, %2" : "=v"(r) : "v"(lo), "v"(hi));
    return r;
}

__device__ __forceinline__ f32x2 dup2(float x) { return (f32x2){x, x}; }

// ---------------- projection GEMM, 32x64 tile, BK=64, 4 waves, z in {0,1,2} ---
// A = X fp32 (cvt_pk inline), B = W fp32 [d][n] staged TRANSPOSED via register
// 4x4 transpose. Grid (12, 16, 3) = 576 blocks (r21 config — fused-z regressed).
//   z=0: Qb = acc + bq (fp32) AND Eq = exp2(c*(acc+bq)) (fp32), both row-major
//   z=1: EkT[col][row0..3] = exp2(c*(acc + bk))   (transposed float4 store)
//   z=2: XWtT[col][row0..3] = bf16(acc)           (transposed uint2 store)
__global__ __launch_bounds__(256) void gemm_proj(
    const float* __restrict__ Xf,
    const float* __restrict__ W0, const float* __restrict__ W1,
    const float* __restrict__ W2,
    const float* __restrict__ bq, const float* __restrict__ bk,
    float* __restrict__ Qb, float* __restrict__ Eq,
    float* __restrict__ EkT, ushort* __restrict__ XWtT)
{
    const int N = D, K = D;
    const int bz = blockIdx.z;

    __shared__ __align__(16) ushort As[32][72];
    __shared__ __align__(16) ushort Bs[64][76];   // 152B rows -> b64 ops

    const int m0 = blockIdx.y * 32;
    const int n0 = blockIdx.x * 64;
    const int t = threadIdx.x;
    const int l = t & 63, w = t >> 6;
    const int wr = w >> 1, wc = w & 1;
    const int frow = l & 15;
    const int kg = (l >> 4) * 8;

    const float* Wm = bz == 0 ? W0 : bz == 1 ? W1 : W2;
    const int srow = t >> 3, sk = (t & 7) * 8;     // A staging
    const int kq = (t >> 4) * 4, nc = (t & 15) * 4; // B staging (4k x 4n block)
    const float* ApF = Xf + (m0 + srow) * D + sk;
    const float* WpF = Wm + kq * D + n0 + nc;

    float4 pa0 = *(const float4*)(ApF + 0);
    float4 pa1 = *(const float4*)(ApF + 4);
    float4 pw0 = *(const float4*)(WpF + 0 * D);
    float4 pw1 = *(const float4*)(WpF + 1 * D);
    float4 pw2 = *(const float4*)(WpF + 2 * D);
    float4 pw3 = *(const float4*)(WpF + 3 * D);

    f32x4 acc[2] = {};

    for (int k0 = 0; k0 < K; k0 += 64) {
        if (k0) __syncthreads();
        {   // A: 8 fp32 -> 4 cvt_pk -> one b128 store
            uint4 av;
            av.x = cvt_pk(pa0.x, pa0.y);
            av.y = cvt_pk(pa0.z, pa0.w);
            av.z = cvt_pk(pa1.x, pa1.y);
            av.w = cvt_pk(pa1.z, pa1.w);
            *(uint4*)&As[srow][sk] = av;
        }
        {   // B: register 4x4 transpose, 2 cvt_pk + 1 b64 store per n-row
            uint2 b;
            b.x = cvt_pk(pw0.x, pw1.x); b.y = cvt_pk(pw2.x, pw3.x);
            *(uint2*)&Bs[nc + 0][kq] = b;
            b.x = cvt_pk(pw0.y, pw1.y); b.y = cvt_pk(pw2.y, pw3.y);
            *(uint2*)&Bs[nc + 1][kq] = b;
            b.x = cvt_pk(pw0.z, pw1.z); b.y = cvt_pk(pw2.z, pw3.z);
            *(uint2*)&Bs[nc + 2][kq] = b;
            b.x = cvt_pk(pw0.w, pw1.w); b.y = cvt_pk(pw2.w, pw3.w);
            *(uint2*)&Bs[nc + 3][kq] = b;
        }
        __syncthreads();
        if (k0 + 64 < K) {                  // prefetch next tile under MFMA
            pa0 = *(const float4*)(ApF + k0 + 64);
            pa1 = *(const float4*)(ApF + k0 + 68);
            pw0 = *(const float4*)(WpF + (k0 + 64) * D);
            pw1 = *(const float4*)(WpF + (k0 + 65) * D);
            pw2 = *(const float4*)(WpF + (k0 + 66) * D);
            pw3 = *(const float4*)(WpF + (k0 + 67) * D);
        }

        bf16x8 af[2];
        #pragma unroll
        for (int kk = 0; kk < 2; ++kk)
            af[kk] = *(const bf16x8*)&As[16 * wr + frow][32 * kk + kg];
        #pragma unroll
        for (int fc = 0; fc < 2; ++fc)
            #pragma unroll
            for (int kk = 0; kk < 2; ++kk) {
                bf16x4 lo = *(const bf16x4*)&Bs[32 * wc + 16 * fc + frow][32 * kk + kg];
                bf16x4 hi = *(const bf16x4*)&Bs[32 * wc + 16 * fc + frow][32 * kk + kg + 4];
                bf16x8 bv = __builtin_shufflevector(lo, hi, 0, 1, 2, 3, 4, 5, 6, 7);
                acc[fc] = __builtin_amdgcn_mfma_f32_16x16x32_bf16(af[kk], bv, acc[fc], 0, 0, 0);
            }
    }

    const int rg = (l >> 4) * 4;
    #pragma unroll
    for (int fc = 0; fc < 2; ++fc) {
        const int col = n0 + 32 * wc + 16 * fc + frow;
        const int row0 = m0 + 16 * wr + rg;       // multiple of 4
        if (bz == 2) {
            uint2 e;
            e.x = cvt_pk(acc[fc][0], acc[fc][1]);
            e.y = cvt_pk(acc[fc][2], acc[fc][3]);
            *(uint2*)&XWtT[col * L + row0] = e;
        } else if (bz == 1) {
            const float bv = bk[col];
            float4 e;
            e.x = __builtin_amdgcn_exp2f(LOG2E2 * (acc[fc][0] + bv));
            e.y = __builtin_amdgcn_exp2f(LOG2E2 * (acc[fc][1] + bv));
            e.z = __builtin_amdgcn_exp2f(LOG2E2 * (acc[fc][2] + bv));
            e.w = __builtin_amdgcn_exp2f(LOG2E2 * (acc[fc][3] + bv));
            *(float4*)&EkT[col * L + row0] = e;
        } else {
            const float bv = bq[col];
            #pragma unroll
            for (int i = 0; i < 4; ++i) {
                float v = acc[fc][i] + bv;
                Qb[(row0 + i) * N + col] = v;
                Eq[(row0 + i) * N + col] = __builtin_amdgcn_exp2f(LOG2E2 * v);
            }
        }
    }
}

// ---------------- output GEMM: out = P @ XWt + bt + Qb, 8 waves ---------------
// 32x64 tile, BK=64, 512 threads (8 waves, each one 16x16 frag), grid (12,16).
__global__ __launch_bounds__(512) void gemm_pv(
    const ushort* __restrict__ Pbf, const ushort* __restrict__ XWtT,
    const float* __restrict__ bt, const float* __restrict__ Qb,
    float* __restrict__ out)
{
    const int N = D, K = L;
    __shared__ __align__(16) ushort As[32][72];
    __shared__ __align__(16) ushort Bs[64][72];

    const int m0 = blockIdx.y * 32;
    const int n0 = blockIdx.x * 64;
    const int t = threadIdx.x;
    const int l = t & 63, w = t >> 6;
    const int wr = w >> 2, wc = w & 3;        // 2 x 4 waves
    const int frow = l & 15;
    const int kg = (l >> 4) * 8;

    const int srA = t >> 4, skA = (t & 15) * 4;   // A: 512 x b64
    const int srB = t >> 3, skB = (t & 7) * 8;    // B: 512 x b128
    const ushort* Ap = Pbf  + (m0 + srA) * K + skA;
    const ushort* Bp = XWtT + (n0 + srB) * K + skB;

    uint2 a0 = *(const uint2*)Ap;
    uint4 b0 = *(const uint4*)Bp;

    f32x4 acc = {};

    for (int k0 = 0; k0 < K; k0 += 64) {
        if (k0) __syncthreads();
        *(uint2*)&As[srA][skA] = a0;
        *(uint4*)&Bs[srB][skB] = b0;
        __syncthreads();
        if (k0 + 64 < K) {
            a0 = *(const uint2*)(Ap + k0 + 64);
            b0 = *(const uint4*)(Bp + k0 + 64);
        }
        #pragma unroll
        for (int kk = 0; kk < 2; ++kk) {
            bf16x8 af = *(const bf16x8*)&As[16 * wr + frow][32 * kk + kg];
            bf16x8 bv = *(const bf16x8*)&Bs[16 * wc + frow][32 * kk + kg];
            acc = __builtin_amdgcn_mfma_f32_16x16x32_bf16(af, bv, acc, 0, 0, 0);
        }
    }

    const int rg = (l >> 4) * 4;
    const int col = n0 + 16 * wc + frow;
    const int row0 = m0 + 16 * wr + rg;
    const float bv = bt[col];
    #pragma unroll
    for (int i = 0; i < 4; ++i)
        out[(row0 + i) * N + col] = acc[i] + bv + Qb[(row0 + i) * N + col];
}

// ---------------- partial scores: lane = k, LDS-broadcast Eq ------------------
// PACKED-FP32 q-pairs + 4-WAY RECIPROCAL (sum w_i/A_i = (N1*CD+N2*AB)*rcp(ABCD)).
// w' = -2*LOG2E*w staged in a contiguous quad array (one b128 per d-quad).
// Partials are in log2 units -> softmax is a bare exp2.
__global__ __launch_bounds__(256) void score_k(
    const float* __restrict__ Eq, const float* __restrict__ EkT,
    const float* __restrict__ w_att, float* __restrict__ sP)
{
    __shared__ __align__(16) float eqlds[DSEG][8];   // eq q0..q7 per d
    __shared__ __align__(16) float wlds[DSEG];       // w' per d (quad-readable)
    const int kt = blockIdx.x;          // 0..1
    const int dh = blockIdx.y;          // 0..7
    const int qg = blockIdx.z;          // 0..63
    const int q0 = qg * QB;
    const int dbase = dh * DSEG;
    const int tid = threadIdx.x;
    const int lane = tid & 63, wv = tid >> 6;
    const int k = kt * 256 + wv * 64 + lane;

    {   // stage: 8 rows x 96 cols, 32 threads per row, 3 cols each
        const int row = tid >> 5;       // 0..7
        const int j   = tid & 31;
        #pragma unroll
        for (int c = 0; c < 3; ++c) {
            int d = j + 32 * c;
            eqlds[d][row] = Eq[(q0 + row) * D + dbase + d];
        }
        if (tid < 32) {
            #pragma unroll
            for (int c = 0; c < 3; ++c) {
                int d = tid + 32 * c;
                wlds[d] = (-2.f * LOG2E) * w_att[dbase + d];
            }
        }
    }
    __syncthreads();

    const float* __restrict__ ekp = EkT + dbase * L + k;
    const f32x2 one = dup2(1.f);
    f32x2 acc2[4] = {};

    #pragma unroll 2
    for (int d0 = 0; d0 < DSEG; d0 += 4) {
        f32x2 ek0 = dup2(ekp[(d0 + 0) * L]);
        f32x2 ek1 = dup2(ekp[(d0 + 1) * L]);
        f32x2 ek2 = dup2(ekp[(d0 + 2) * L]);
        f32x2 ek3 = dup2(ekp[(d0 + 3) * L]);
        f32x4 wq4 = *(const f32x4*)&wlds[d0];
        f32x2 w0 = dup2(wq4[0]), w1 = dup2(wq4[1]);
        f32x2 w2 = dup2(wq4[2]), w3 = dup2(wq4[3]);
        f32x4 Elo[4], Ehi[4];
        #pragma unroll
        for (int dd = 0; dd < 4; ++dd) {
            Elo[dd] = *(const f32x4*)&eqlds[d0 + dd][0];   // q0..q3
            Ehi[dd] = *(const f32x4*)&eqlds[d0 + dd][4];   // q4..q7
        }
        #pragma unroll
        for (int j = 0; j < 4; ++j) {
            #define GET2(dd) ((j < 2) ? (f32x2){Elo[dd][2 * j], Elo[dd][2 * j + 1]} \
                                      : (f32x2){Ehi[dd][2 * j - 4], Ehi[dd][2 * j - 3]})
            f32x2 e0 = GET2(0);
            f32x2 e1 = GET2(1);
            f32x2 e2 = GET2(2);
            f32x2 e3 = GET2(3);
            #undef GET2
            f32x2 Aa = __builtin_elementwise_fma(e0, ek0, one);
            f32x2 Bb = __builtin_elementwise_fma(e1, ek1, one);
            f32x2 Cc = __builtin_elementwise_fma(e2, ek2, one);
            f32x2 Dd = __builtin_elementwise_fma(e3, ek3, one);
            f32x2 AB = Aa * Bb, CD = Cc * Dd;
            f32x2 N1 = __builtin_elementwise_fma(w0, Bb, w1 * Aa);
            f32x2 N2 = __builtin_elementwise_fma(w2, Dd, w3 * Cc);
            f32x2 Nm = __builtin_elementwise_fma(N1, CD, N2 * AB);
            f32x2 P = AB * CD;
            f32x2 R;
            R.x = __builtin_amdgcn_rcpf(P.x);
            R.y = __builtin_amdgcn_rcpf(P.y);
            acc2[j] = __builtin_elementwise_fma(Nm, R, acc2[j]);
        }
    }

    float* __restrict__ dst = sP + dh * LL + q0 * L + k;
    #pragma unroll
    for (int j = 0; j < 4; ++j) {
        dst[(2 * j + 0) * L] = acc2[j].x;
        dst[(2 * j + 1) * L] = acc2[j].y;
    }
}

// ---------------- softmax (sum of 8 d-partials + mask) -> bf16 probs ----------
// 512 blocks (one q-row each) x 512 threads. NO max pass (bounded log2 scores).
__global__ __launch_bounds__(512) void softmax_probs(
    const float* __restrict__ sP, const float* __restrict__ mask,
    ushort* __restrict__ Pbf)
{
    __shared__ float redB[8];
    const int q = blockIdx.x;
    const int tid = threadIdx.x;
    const int lane = tid & 63, wave = tid >> 6;

    float v = LOG2E * mask[tid];
    #pragma unroll
    for (int h = 0; h < DH; ++h)
        v += sP[h * LL + q * L + tid];

    float e = __builtin_amdgcn_exp2f(v);
    float s = e;
    #pragma unroll
    for (int off = 32; off; off >>= 1)
        s += __shfl_xor(s, off);
    if (lane == 0) redB[wave] = s;
    __syncthreads();
    float t0 = redB[0];
    #pragma unroll
    for (int i = 1; i < 8; ++i) t0 += redB[i];
    Pbf[q * L + tid] = f2bf(e * __builtin_amdgcn_rcpf(t0));
}

extern "C" void kernel_launch(void* const* d_in, const int* in_sizes, int n_in,
                              void* d_out, int out_size, void* d_ws, size_t ws_size,
                              hipStream_t stream) {
    const float* X     = (const float*)d_in[0];
    const float* mask  = (const float*)d_in[1];
    const float* Wq    = (const float*)d_in[2];
    const float* bq    = (const float*)d_in[3];
    const float* Wk    = (const float*)d_in[4];
    const float* bk    = (const float*)d_in[5];
    const float* w_att = (const float*)d_in[6];
    // d_in[7] = b_att: row-constant -> softmax-invariant; dropped.
    const float* Wt    = (const float*)d_in[8];
    const float* bt    = (const float*)d_in[9];
    float* out = (float*)d_out;

    const int LD = L * D;
    float*  Qb   = (float*)d_ws;          // [L*D] fp32 Q (final addend)
    float*  Eq   = Qb + LD;               // [L*D] exp2(c*Q) row-major
    float*  EkT  = Eq + LD;               // [D][L] exp2(c*K) transposed
    float*  sP   = EkT + LD;              // [DH][L][L] partial scores (log2 units)
    ushort* XWtT = (ushort*)(sP + DH * LL); // [D][L] bf16 (X@Wt)^T
    ushort* Pbf  = XWtT + LD;             // [L][L] bf16 probs

    // z=0: Qb+Eq ; z=1: EkT ; z=2: XWtT   (576 blocks — r21 config)
    gemm_proj<<<dim3(D / 64, L / 32, 3), 256, 0, stream>>>(
        X, Wq, Wk, Wt, bq, bk, Qb, Eq, EkT, XWtT);

    // partial scores: lane = k, LDS-broadcast Eq, packed-fp32 4-way rcp
    score_k<<<dim3(2, DH, L / QB), 256, 0, stream>>>(Eq, EkT, w_att, sP);

    // softmax over the 8 partials (+mask) -> bf16 probs, 1 q-row per block
    softmax_probs<<<dim3(L), 512, 0, stream>>>(sP, mask, Pbf);

    // out = P @ XWt + bt + Q   (K=512, 8 waves)
    gemm_pv<<<dim3(D / 64, L / 32), 512, 0, stream>>>(Pbf, XWtT, bt, Qb, out);
}